// Round 10
// baseline (53.923 us; speedup 1.0000x reference)
//
#include <hip/hip_runtime.h>

#define NT 256

typedef float f32x2 __attribute__((ext_vector_type(2)));

#if defined(__has_builtin)
#if __has_builtin(__builtin_amdgcn_exp2f)
#define EXP2F __builtin_amdgcn_exp2f
#else
#define EXP2F exp2f
#endif
#else
#define EXP2F exp2f
#endif

__device__ __forceinline__ float rfl(float x) {
    return __uint_as_float(__builtin_amdgcn_readfirstlane(__float_as_uint(x)));
}
__device__ __forceinline__ f32x2 bc2(float w) {
    f32x2 r; r.x = w; r.y = w; return r;
}
__device__ __forceinline__ f32x2 pfma(f32x2 a, f32x2 b, f32x2 c) {
    return __builtin_elementwise_fma(a, b, c);
}

// 4 sigmoids x 2 samples, reciprocal shared 4-ways per element:
// 8 exp2 + 2 rcp + ~17 packed VALU. sigmoid(a)=1/(1+exp2(-log2e*a)).
// |a|<~20 -> all intermediates < 2^88: no overflow/NaN. rel-err ~2e-6.
__device__ __forceinline__ void sig4(f32x2 v[4]) {
    const f32x2 C   = bc2(-1.442695040888963f);
    const f32x2 ONE = bc2(1.0f);
    f32x2 d[4];
    #pragma unroll
    for (int h = 0; h < 4; h++) {
        f32x2 m = v[h] * C;
        f32x2 e; e.x = EXP2F(m.x); e.y = EXP2F(m.y);
        d[h] = e + ONE;
    }
    f32x2 p01 = d[0] * d[1];
    f32x2 p23 = d[2] * d[3];
    f32x2 P   = p01 * p23;
    f32x2 r;
    r.x = __builtin_amdgcn_rcpf(P.x);
    r.y = __builtin_amdgcn_rcpf(P.y);
    f32x2 r01 = r * p23;
    f32x2 r23 = r * p01;
    v[0] = r01 * d[1];
    v[1] = r01 * d[0];
    v[2] = r23 * d[3];
    v[3] = r23 * d[2];
}

// repack 20 consecutive floats (4 samples x 5 feats, via 5 float4) into
// two per-feature pair-sets: A = samples {0,1}, B = samples {2,3}
__device__ __forceinline__ void repack(const float4 L[5], f32x2 A[5], f32x2 B[5]) {
    const float* f = (const float*)L;
    #pragma unroll
    for (int q = 0; q < 5; q++) {
        A[q].x = f[q];      A[q].y = f[5 + q];
        B[q].x = f[10 + q]; B[q].y = f[15 + q];
    }
}

__global__ __launch_bounds__(NT, 2)
void mlp6_spt4(const float* __restrict__ xl,
               const float* __restrict__ yl,
               const float* __restrict__ xr,
               const float* __restrict__ W1, const float* __restrict__ b1,
               const float* __restrict__ W2, const float* __restrict__ b2,
               const float* __restrict__ W3_2, const float* __restrict__ b3_2,
               const float* __restrict__ W3_1, const float* __restrict__ b3_1,
               const float* __restrict__ W4, const float* __restrict__ b4,
               float* __restrict__ out, int nq4)
{
    int g4 = blockIdx.x * NT + threadIdx.x;
    if (g4 >= nq4) g4 = nq4 - 1;             // clamped dup-writes are identical

    // ---- fold fc3(+fc4): per-branch 4-vec fw + output biases (uniform) ----
    // W3_2 flat [4][2][4] rows j=0..3 <-> branches {0,1,4,5}; W4 flat [2][1][4];
    // W3_1 flat [2][1][4]; b3_2 flat [4][2]; b3_1 flat [2][1]; b4 flat [2][1].
    float fw[6][4];
    #pragma unroll
    for (int h = 0; h < 4; h++) {
        fw[0][h] = rfl(fmaf(W4[1], W3_2[4 + h],  W4[0] * W3_2[h]));
        fw[1][h] = rfl(fmaf(W4[5], W3_2[12 + h], W4[4] * W3_2[8 + h]));
        fw[2][h] = rfl(W3_1[h]);
        fw[3][h] = rfl(W3_1[4 + h]);
        fw[4][h] = rfl(fmaf(W4[3], W3_2[20 + h], W4[2] * W3_2[16 + h]));
        fw[5][h] = rfl(fmaf(W4[7], W3_2[28 + h], W4[6] * W3_2[24 + h]));
    }
    float fb0 = rfl(b3_1[0]);
    float fb1 = rfl(b3_1[1]);
    float fb2 = rfl(W4[0]*b3_2[0] + W4[1]*b3_2[1] + W4[2]*b3_2[4] + W4[3]*b3_2[5] + b4[0]);
    float fb3 = rfl(W4[4]*b3_2[2] + W4[5]*b3_2[3] + W4[6]*b3_2[6] + W4[7]*b3_2[7] + b4[1]);

    f32x2 o0A = bc2(fb0), o0B = bc2(fb0);
    f32x2 o1A = bc2(fb1), o1B = bc2(fb1);
    f32x2 o2A = bc2(fb2), o2B = bc2(fb2);
    f32x2 o3A = bc2(fb3), o3B = bc2(fb3);

    // one branch over TWO pair-sets; every uniform broadcast serves both chains
    auto br = [&](int k, const f32x2 (&inA)[5], const f32x2 (&inB)[5],
                  const float fwk[4], f32x2& oA, f32x2& oB) {
        f32x2 hA[4], hB[4];
        #pragma unroll
        for (int hh = 0; hh < 4; hh++) {
            f32x2 w0 = bc2(W1[k*20 + hh*5]);
            f32x2 aA = inA[0] * w0;
            f32x2 aB = inB[0] * w0;
            #pragma unroll
            for (int q = 1; q < 5; q++) {
                f32x2 wq = bc2(W1[k*20 + hh*5 + q]);
                aA = pfma(inA[q], wq, aA);
                aB = pfma(inB[q], wq, aB);
            }
            f32x2 bb = bc2(b1[k*4 + hh]);
            hA[hh] = aA + bb;
            hB[hh] = aB + bb;
        }
        sig4(hA); sig4(hB);
        f32x2 cA[4], cB[4];
        #pragma unroll
        for (int g = 0; g < 4; g++) {
            f32x2 w0 = bc2(W2[k*16 + g*4]);
            f32x2 aA = hA[0] * w0;
            f32x2 aB = hB[0] * w0;
            #pragma unroll
            for (int q = 1; q < 4; q++) {
                f32x2 wq = bc2(W2[k*16 + g*4 + q]);
                aA = pfma(hA[q], wq, aA);
                aB = pfma(hB[q], wq, aB);
            }
            f32x2 bb = bc2(b2[k*4 + g]);
            cA[g] = aA + bb;
            cB[g] = aB + bb;
        }
        sig4(cA); sig4(cB);
        #pragma unroll
        for (int g = 0; g < 4; g++) {
            f32x2 wg = bc2(fwk[g]);
            oA = pfma(cA[g], wg, oA);
            oB = pfma(cB[g], wg, oB);
        }
    };

    const float4* x4 = (const float4*)xl + (long long)g4 * 5;
    const float4* y4 = (const float4*)yl + (long long)g4 * 5;
    const float4* c4 = (const float4*)xr + (long long)g4 * 5;

    // X = stack([xl, yl, xr, yl, xl, yl]); slots: br2->o0, br3->o1,
    // {br0,br4}->o2, {br1,br5}->o3. Phased: xl -> yl -> xr.
    {
        float4 L[5];
        #pragma unroll
        for (int q = 0; q < 5; q++) L[q] = x4[q];
        f32x2 A[5], Bp[5];
        repack(L, A, Bp);
        br(0, A, Bp, fw[0], o2A, o2B);
        br(4, A, Bp, fw[4], o2A, o2B);
    }
    {
        float4 L[5];
        #pragma unroll
        for (int q = 0; q < 5; q++) L[q] = y4[q];
        f32x2 A[5], Bp[5];
        repack(L, A, Bp);
        br(1, A, Bp, fw[1], o3A, o3B);
        br(3, A, Bp, fw[3], o1A, o1B);
        br(5, A, Bp, fw[5], o3A, o3B);
    }
    {
        float4 L[5];
        #pragma unroll
        for (int q = 0; q < 5; q++) L[q] = c4[q];
        f32x2 A[5], Bp[5];
        repack(L, A, Bp);
        br(2, A, Bp, fw[2], o0A, o0B);
    }

    // 4 samples x 16B = 64B contiguous per thread
    float4* out4 = (float4*)out + (long long)g4 * 4;
    float4 r;
    r.x = o0A.x; r.y = o1A.x; r.z = o2A.x; r.w = o3A.x; out4[0] = r;
    r.x = o0A.y; r.y = o1A.y; r.z = o2A.y; r.w = o3A.y; out4[1] = r;
    r.x = o0B.x; r.y = o1B.x; r.z = o2B.x; r.w = o3B.x; out4[2] = r;
    r.x = o0B.y; r.y = o1B.y; r.z = o2B.y; r.w = o3B.y; out4[3] = r;
}

extern "C" void kernel_launch(void* const* d_in, const int* in_sizes, int n_in,
                              void* d_out, int out_size, void* d_ws, size_t ws_size,
                              hipStream_t stream) {
    const float* xl   = (const float*)d_in[0];
    const float* yl   = (const float*)d_in[1];
    const float* xr   = (const float*)d_in[2];
    // d_in[3] = yr — unused by the reference forward
    const float* W1   = (const float*)d_in[4];
    const float* b1   = (const float*)d_in[5];
    const float* W2   = (const float*)d_in[6];
    const float* b2   = (const float*)d_in[7];
    const float* W3_2 = (const float*)d_in[8];
    const float* b3_2 = (const float*)d_in[9];
    const float* W3_1 = (const float*)d_in[10];
    const float* b3_1 = (const float*)d_in[11];
    const float* W4   = (const float*)d_in[12];
    const float* b4   = (const float*)d_in[13];
    float* out = (float*)d_out;

    int B   = in_sizes[0] / 5;             // 2,000,000 (divisible by 4)
    int nq4 = B >> 2;                      // 500,000 sample-quads
    int blocks = (nq4 + NT - 1) / NT;
    mlp6_spt4<<<blocks, NT, 0, stream>>>(
        xl, yl, xr, W1, b1, W2, b2, W3_2, b3_2, W3_1, b3_1, W4, b4, out, nq4);
}